// Round 6
// baseline (499.280 us; speedup 1.0000x reference)
//
#include <hip/hip_runtime.h>
#include <math.h>

#define BQ 4096
#define F_SUP 5
#define MAXK 64
#define ED 128
#define DM 256
#define DI 512
#define LH 512
#define NG 2048
#define PADX 200000
#define KNB 10
#define MROWS 82048           // 8202*10 padded to 641*128
#define MREAL 82020
#define MQ 4224               // 4101 rows padded to 33*128

typedef unsigned short u16;
typedef __attribute__((ext_vector_type(8))) short short8;
typedef __attribute__((ext_vector_type(4))) float floatx4;

__device__ __forceinline__ float sigf(float x) { return 1.0f / (1.0f + __expf(-x)); }
__device__ __forceinline__ float tanh_fast(float x) {
  float a = fabsf(x);
  float e = __expf(-2.0f * a);
  float t = (1.0f - e) / (1.0f + e);
  return copysignf(t, x);
}
__device__ __forceinline__ u16 f2bf(float f) {
  unsigned u = __float_as_uint(f);
  unsigned r = (u + 0x7FFFu + ((u >> 16) & 1u)) >> 16;
  return (u16)r;
}
__device__ __forceinline__ float bf2f(u16 u) {
  return __uint_as_float(((unsigned)u) << 16);
}

// ============ phase A: gather + sims + top-k -> selected symbol ids ============
__global__ __launch_bounds__(256) void nbr_topk_kernel(
    const int* __restrict__ query, const int* __restrict__ support,
    const int* __restrict__ q_l1, const int* __restrict__ q_r1,
    const int* __restrict__ s_l1, const int* __restrict__ s_r1,
    const float* __restrict__ emb,
    int* __restrict__ idxA, int* __restrict__ meta)
{
  __shared__ int relS[64], entS[64];
  __shared__ __align__(16) float sE[128];
  __shared__ float simS[64];
  __shared__ int selS[16];
  __shared__ int cntS;
  __shared__ float nsS;

  int tid = threadIdx.x;
  int b = blockIdx.x;
  const int* conn; int self_id;
  if (b < BQ)              { int i = b;              conn = q_l1 + i*(MAXK*2); self_id = query[2*i];   }
  else if (b < 2*BQ)       { int i = b - BQ;         conn = q_r1 + i*(MAXK*2); self_id = query[2*i+1]; }
  else if (b < 2*BQ+F_SUP) { int i = b - 2*BQ;       conn = s_l1 + i*(MAXK*2); self_id = support[2*i]; }
  else                     { int i = b - 2*BQ-F_SUP; conn = s_r1 + i*(MAXK*2); self_id = support[2*i+1]; }

  if (tid < 128) {
    int v = conn[tid];
    if (tid & 1) entS[tid >> 1] = v; else relS[tid >> 1] = v;
    sE[tid] = emb[(long)self_id * ED + tid];
  }
  __syncthreads();
  if (tid < 64) {
    float v = sE[tid]*sE[tid] + sE[tid+64]*sE[tid+64];
    #pragma unroll
    for (int off = 1; off < 64; off <<= 1) v += __shfl_xor(v, off);
    if (tid == 0) nsS = fmaxf(sqrtf(v), 1e-12f);
  }
  __syncthreads();

  {
    int k = tid >> 2, part = tid & 3;
    const float* er = emb + (long)entS[k] * ED + part * 32;
    const float* sr = &sE[part * 32];
    float dot = 0.f, sq = 0.f;
    #pragma unroll
    for (int j = 0; j < 32; j += 4) {
      float4 e = *(const float4*)(er + j);
      float4 s = *(const float4*)(sr + j);
      dot += e.x*s.x + e.y*s.y + e.z*s.z + e.w*s.w;
      sq  += e.x*e.x + e.y*e.y + e.z*e.z + e.w*e.w;
    }
    dot += __shfl_xor(dot, 1); dot += __shfl_xor(dot, 2);
    sq  += __shfl_xor(sq, 1);  sq  += __shfl_xor(sq, 2);
    if (part == 0) {
      float ne = fmaxf(sqrtf(sq), 1e-12f);
      float sim = dot / (nsS * ne);
      if (relS[k] == PADX) sim -= 1e9f;
      simS[k] = sim;
    }
  }
  __syncthreads();

  if (tid < 64) {
    float mys = simS[tid];
    int rank = 0;
    #pragma unroll
    for (int j = 0; j < 64; ++j) {
      float s = simS[j];
      rank += ((s > mys) || (s == mys && j < tid)) ? 1 : 0;
    }
    bool val = (rank < KNB) && (relS[tid] != PADX);
    unsigned long long vm = __ballot(val ? 1 : 0);
    if (val) {
      int pos = __popcll(vm & ((1ull << tid) - 1ull));
      selS[pos] = tid;
    }
    if (tid == 0) { cntS = __popcll(vm); meta[b] = __popcll(vm); }
  }
  __syncthreads();

  int cnt = cntS;
  long base = (long)b * 10;
  if (tid < 2 * KNB) {
    int kk = tid >> 1, h = tid & 1;
    int id = PADX;                                  // PAD row of emb is all zeros
    if (kk < cnt) { int k = selS[kk]; id = h ? entS[k] : relS[k]; }
    idxA[(base + kk) * 2 + h] = id;
  }
  if (b == 0 && tid >= 128 && tid < 128 + 2 * (MROWS - MREAL)) {
    idxA[(long)MREAL * 2 + (tid - 128)] = PADX;     // pad rows -> zero emb row
  }
}

// ============ proj GEMM, LDS-free, gather fused into fragment loads ============
// proj[M,128] = bf16(emb[idx]) @ gcn_w^T.  A-fragment = 8 contiguous K per lane.
__global__ __launch_bounds__(256) void proj_gather_gemm(
    const int* __restrict__ idxA, const float* __restrict__ emb,
    const u16* __restrict__ W, u16* __restrict__ proj)
{
  int tid = threadIdx.x;
  int bm = blockIdx.x;
  int lane = tid & 63, wave = tid >> 6;
  int wm = (wave & 1) * 64, wn = (wave >> 1) * 64;
  int col = lane & 15, quad = lane >> 4;

  int ids[4][2];
  #pragma unroll
  for (int i = 0; i < 4; ++i) {
    int row = bm * 128 + wm + i * 16 + col;
    ids[i][0] = idxA[row * 2];        // rel (K cols 0..127)
    ids[i][1] = idxA[row * 2 + 1];    // ent (K cols 128..255)
  }
  const u16* Bbase = W + (long)(wn + col) * 256 + quad * 8;

  floatx4 acc[4][4];
  #pragma unroll
  for (int i = 0; i < 4; ++i)
    #pragma unroll
    for (int j = 0; j < 4; ++j) { floatx4 z = {0.f,0.f,0.f,0.f}; acc[i][j] = z; }

  #pragma unroll 2
  for (int k0 = 0; k0 < 256; k0 += 32) {
    int hsel = k0 >> 7;                       // half select (uniform per chunk)
    int kk = (k0 & 127) + quad * 8;
    short8 af[4], bfr[4];
    #pragma unroll
    for (int i = 0; i < 4; ++i) {
      const float* src = emb + (long)ids[i][hsel] * ED + kk;
      float4 f0 = *(const float4*)(src);
      float4 f1 = *(const float4*)(src + 4);
      short8 s;
      s[0]=(short)f2bf(f0.x); s[1]=(short)f2bf(f0.y); s[2]=(short)f2bf(f0.z); s[3]=(short)f2bf(f0.w);
      s[4]=(short)f2bf(f1.x); s[5]=(short)f2bf(f1.y); s[6]=(short)f2bf(f1.z); s[7]=(short)f2bf(f1.w);
      af[i] = s;
    }
    #pragma unroll
    for (int j = 0; j < 4; ++j)
      bfr[j] = *(const short8*)(Bbase + (long)j * 16 * 256 + k0);
    #pragma unroll
    for (int i = 0; i < 4; ++i)
      #pragma unroll
      for (int j = 0; j < 4; ++j)
        acc[i][j] = __builtin_amdgcn_mfma_f32_16x16x32_bf16(af[i], bfr[j], acc[i][j], 0, 0, 0);
  }
  int gm0 = bm * 128 + wm + quad * 4;
  int gn0 = wn + col;
  #pragma unroll
  for (int i = 0; i < 4; ++i)
    #pragma unroll
    for (int j = 0; j < 4; ++j)
      #pragma unroll
      for (int rr = 0; rr < 4; ++rr)
        proj[(long)(gm0 + i * 16 + rr) * 128 + gn0 + j * 16] = f2bf(acc[i][j][rr]);
}

// ============ phase C: leaky/sum + gate MLP + tanh output ============
__global__ __launch_bounds__(128) void nbr_post_kernel(
    const int* __restrict__ query, const int* __restrict__ support,
    const int* __restrict__ q_deg_l, const int* __restrict__ q_deg_r,
    const int* __restrict__ s_deg_l, const int* __restrict__ s_deg_r,
    const float* __restrict__ emb,
    const u16* __restrict__ proj, const int* __restrict__ meta,
    const float* __restrict__ gcn_w_b, const float* __restrict__ gcn_b,
    const float* __restrict__ g1_w, const float* __restrict__ g1_b,
    const float* __restrict__ ln1_g, const float* __restrict__ ln1_b,
    const float* __restrict__ g2_w, const float* __restrict__ g2_b,
    const float* __restrict__ gate_temp,
    float* __restrict__ qv, u16* __restrict__ qv_bf)
{
  __shared__ __align__(16) float aggS[128];
  __shared__ float sEs[128];
  __shared__ float gateS;
  int tid = threadIdx.x, b = blockIdx.x;
  int deg, self_id, row, colb;
  if (b < BQ)              { int i = b;              deg = q_deg_l[i]; self_id = query[2*i];     row = i;        colb = 0;  }
  else if (b < 2*BQ)       { int i = b - BQ;         deg = q_deg_r[i]; self_id = query[2*i+1];   row = i;        colb = ED; }
  else if (b < 2*BQ+F_SUP) { int i = b - 2*BQ;       deg = s_deg_l[i]; self_id = support[2*i];   row = BQ + i;   colb = 0;  }
  else                     { int i = b - 2*BQ-F_SUP; deg = s_deg_r[i]; self_id = support[2*i+1]; row = BQ + i;   colb = ED; }
  float* outp = qv + (long)row * DM + colb;
  u16*  outpb = qv_bf + (long)row * DM + colb;

  int cnt = meta[b];
  float denom = fmaxf((float)cnt, 1.0f);
  float bsum = gcn_w_b[tid] + gcn_b[tid];
  float agg = 0.f;
  long pbase = (long)b * 10;
  for (int kk = 0; kk < cnt; ++kk) {
    float z = bf2f(proj[(pbase + kk) * 128 + tid]) + bsum;
    z = (z >= 0.f) ? z : 0.01f * z;
    agg += z;
  }
  agg /= denom;
  aggS[tid] = agg;
  sEs[tid] = emb[(long)self_id * ED + tid];
  __syncthreads();

  if (tid < 64) {
    int e = tid;
    const float4* g1r = (const float4*)(g1_w + e * ED);
    float y = g1_b[e];
    #pragma unroll 8
    for (int j = 0; j < 32; ++j) {
      float4 w = g1r[j];
      float4 a = *(const float4*)&aggS[j * 4];
      y += w.x*a.x + w.y*a.y + w.z*a.z + w.w*a.w;
    }
    float s = y;
    #pragma unroll
    for (int off = 1; off < 64; off <<= 1) s += __shfl_xor(s, off);
    float mean = s * (1.0f / 64.0f);
    float dv = y - mean;
    float s2 = dv * dv;
    #pragma unroll
    for (int off = 1; off < 64; off <<= 1) s2 += __shfl_xor(s2, off);
    float var = s2 * (1.0f / 64.0f);
    float hv = dv / sqrtf(var + 1e-5f) * ln1_g[e] + ln1_b[e];
    hv = fmaxf(hv, 0.f);
    float lp = hv * g2_w[e];
    #pragma unroll
    for (int off = 1; off < 64; off <<= 1) lp += __shfl_xor(lp, off);
    if (e == 0) {
      float logit = lp + g2_b[0];
      float temp = fminf(fmaxf(gate_temp[0], 0.1f), 5.0f);
      float gate = 1.0f / (1.0f + expf(-logit / temp));
      if (deg <= 0) gate = 0.f;
      gateS = gate;
    }
  }
  __syncthreads();
  float o = tanhf(sEs[tid] + gateS * aggS[tid]);
  outp[tid] = o;
  outpb[tid] = f2bf(o);
}

// ============ LDS-free MFMA bf16 GEMM. lstm_mode: 0 none, 1 LSTM step, 2 first LSTM step.
// Fragments loaded directly from global (16B/lane, line-coalesced per wave, L2-served).
// LSTM modes: j=gate permutation (gate=j, unit u=bn*32+wnx*16+col); gq/cstate in
// C-fragment order (fb=(blk*4+wave)*64+lane).
template<int K>
__global__ __launch_bounds__(256) void mfma_gemm(
    const u16* __restrict__ A, int lda,
    const u16* __restrict__ W, int ldw,
    int N,
    float* __restrict__ Cout, u16* __restrict__ Cbf,
    const float* __restrict__ bias0,
    const u16* __restrict__ gqin,       // lstm_mode==1: fragment-order gates input
    u16* __restrict__ gqout,            // lstm_mode==2: fragment-order gates output
    int relu, int lstm_mode,
    float* __restrict__ cstate, const float* __restrict__ qe,
    u16* __restrict__ hbf)
{
  int tid = threadIdx.x;
  int nb = N >> 7;
  int bn = blockIdx.x % nb, bm = blockIdx.x / nb;
  int lane = tid & 63, wave = tid >> 6;
  int wm = (wave & 1) * 64, wn = (wave >> 1) * 64;
  int col = lane & 15, quad = lane >> 4;

  // ---- epilogue input prefetch (latency hides under the K-loop) ----
  u16 gqa[64]; float cpv[16]; float qev[16]; float scv[4];
  int u = 0; long fb = 0;
  if (lstm_mode) {
    u = bn * 32 + (wave >> 1) * 16 + col;
    fb = ((long)blockIdx.x * 4 + wave) * 64 + lane;
    #pragma unroll
    for (int j = 0; j < 4; ++j)
      scv[j] = bias0[bn * 128 + (wave >> 1) * 64 + j * 16 + col];
    if (lstm_mode == 1) {
      const short8* gp = (const short8*)(gqin + fb * 64);
      #pragma unroll
      for (int t = 0; t < 8; ++t) *(short8*)&gqa[t * 8] = gp[t];
      const float4* cp = (const float4*)(cstate + fb * 16);
      #pragma unroll
      for (int t = 0; t < 4; ++t) *(float4*)&cpv[t * 4] = cp[t];
    }
    if (u < DM) {
      #pragma unroll
      for (int i = 0; i < 4; ++i)
        #pragma unroll
        for (int r = 0; r < 4; ++r) {
          int m = bm * 128 + (wave & 1) * 64 + i * 16 + quad * 4 + r;
          qev[i * 4 + r] = qe[(long)m * DM + u];
        }
    }
  }

  const u16* Abase = A + (long)(bm * 128 + wm + col) * lda + quad * 8;
  const u16* Bbase = W + (long)(bn * 128 + wn + col) * ldw + quad * 8;

  floatx4 acc[4][4];
  #pragma unroll
  for (int i = 0; i < 4; ++i)
    #pragma unroll
    for (int j = 0; j < 4; ++j) { floatx4 z = {0.f,0.f,0.f,0.f}; acc[i][j] = z; }

  #pragma unroll 2
  for (int k0 = 0; k0 < K; k0 += 32) {
    short8 af[4], bfr[4];
    #pragma unroll
    for (int i = 0; i < 4; ++i)
      af[i] = *(const short8*)(Abase + (long)i * 16 * lda + k0);
    #pragma unroll
    for (int j = 0; j < 4; ++j)
      bfr[j] = *(const short8*)(Bbase + (long)j * 16 * ldw + k0);
    #pragma unroll
    for (int i = 0; i < 4; ++i)
      #pragma unroll
      for (int j = 0; j < 4; ++j)
        acc[i][j] = __builtin_amdgcn_mfma_f32_16x16x32_bf16(af[i], bfr[j], acc[i][j], 0, 0, 0);
  }

  if (lstm_mode) {
    float cnew[16];
    #pragma unroll
    for (int i = 0; i < 4; ++i) {
      #pragma unroll
      for (int r = 0; r < 4; ++r) {
        float gI = acc[i][0][r] + scv[0];
        float gF = acc[i][1][r] + scv[1];
        float gG = acc[i][2][r] + scv[2];
        float gO = acc[i][3][r] + scv[3];
        if (lstm_mode == 1) {
          gI += bf2f(gqa[(i * 4 + 0) * 4 + r]);
          gF += bf2f(gqa[(i * 4 + 1) * 4 + r]);
          gG += bf2f(gqa[(i * 4 + 2) * 4 + r]);
          gO += bf2f(gqa[(i * 4 + 3) * 4 + r]);
        }
        float cp = (lstm_mode == 2) ? 0.f : cpv[i * 4 + r];
        float cn = sigf(gF) * cp + sigf(gI) * tanh_fast(gG);
        cnew[i * 4 + r] = cn;
        if (u < DM) {
          int m = bm * 128 + (wave & 1) * 64 + i * 16 + quad * 4 + r;
          hbf[(long)m * DM + u] = f2bf(qev[i * 4 + r] + sigf(gO) * tanh_fast(cn));
        }
      }
    }
    {
      float4* cp = (float4*)(cstate + fb * 16);
      #pragma unroll
      for (int t = 0; t < 4; ++t) cp[t] = *(float4*)&cnew[t * 4];
    }
    if (lstm_mode == 2) {
      u16 ga[64];
      #pragma unroll
      for (int i = 0; i < 4; ++i)
        #pragma unroll
        for (int j = 0; j < 4; ++j)
          #pragma unroll
          for (int r = 0; r < 4; ++r)
            ga[(i * 4 + j) * 4 + r] = f2bf(acc[i][j][r] + scv[j]);
      short8* gp = (short8*)(gqout + fb * 64);
      #pragma unroll
      for (int t = 0; t < 8; ++t) gp[t] = *(short8*)&ga[t * 8];
    }
  } else {
    int gm0 = bm * 128 + wm + quad * 4;
    int gn0 = bn * 128 + wn + col;
    #pragma unroll
    for (int i = 0; i < 4; ++i) {
      #pragma unroll
      for (int j = 0; j < 4; ++j) {
        int n = gn0 + j * 16;
        #pragma unroll
        for (int r = 0; r < 4; ++r) {
          int m = gm0 + i * 16 + r;
          float v = acc[i][j][r];
          if (bias0) v += bias0[n];
          if (relu) v = fmaxf(v, 0.f);
          if (Cout) Cout[(long)m * N + n] = v;
          if (Cbf)  Cbf[(long)m * N + n] = f2bf(v);
        }
      }
    }
  }
}

// ============ weight casts + j=gate permuted layouts ============
// position p in [0,2048): g=(p>>4)&3, u=(p>>7)*32+((p>>6)&1)*16+(p&15), orig row n=g*512+u
__global__ void prep_cast(
    const float* __restrict__ p1, const float* __restrict__ p2,
    const float* __restrict__ gcnw, const float* __restrict__ wih,
    const float* __restrict__ whh, const float* __restrict__ bih,
    const float* __restrict__ bhh,
    u16* __restrict__ p1b, u16* __restrict__ p2b, u16* __restrict__ gcnb,
    u16* __restrict__ wihb, u16* __restrict__ whhb, float* __restrict__ bihh)
{
  int gid = blockIdx.x * 256 + threadIdx.x;
  if (gid < 131072) { p1b[gid] = f2bf(p1[gid]); }
  else if (gid < 262144) { int i = gid - 131072; p2b[i] = f2bf(p2[i]); }
  else if (gid < 294912) { int i = gid - 262144; gcnb[i] = f2bf(gcnw[i]); }
  else if (gid < 819200) {
    int i = gid - 294912; int p = i >> 8, k = i & 255;
    int g = (p >> 4) & 3, uu = (p >> 7) * 32 + ((p >> 6) & 1) * 16 + (p & 15);
    int n = g * 512 + uu;
    wihb[i] = f2bf(wih[(long)n * DM + k]);
  } else if (gid < 1343488) {
    int i = gid - 819200; int p = i >> 8, k = i & 255;
    int g = (p >> 4) & 3, uu = (p >> 7) * 32 + ((p >> 6) & 1) * 16 + (p & 15);
    int n = g * 512 + uu;
    whhb[i] = f2bf(whh[(long)n * LH + k]);
  } else if (gid < 1345536) {
    int p = gid - 1343488;
    int g = (p >> 4) & 3, uu = (p >> 7) * 32 + ((p >> 6) & 1) * 16 + (p & 15);
    int n = g * 512 + uu;
    bihh[p] = bih[n] + bhh[n];
  }
}

// ============ residual layernorm -> qe (fp32 + bf16), rows 0..4100 ============
__global__ __launch_bounds__(256) void ln_residual_kernel(
    const float* __restrict__ h2buf, const float* __restrict__ xbuf,
    const float* __restrict__ lng, const float* __restrict__ lnb,
    float* __restrict__ out, u16* __restrict__ outb)
{
  __shared__ float red[4];
  int r = blockIdx.x, tid = threadIdx.x;
  float v = h2buf[(long)r * DM + tid] + xbuf[(long)r * DM + tid];
  float s = v;
  #pragma unroll
  for (int off = 1; off < 64; off <<= 1) s += __shfl_xor(s, off);
  if ((tid & 63) == 0) red[tid >> 6] = s;
  __syncthreads();
  float mean = (red[0] + red[1] + red[2] + red[3]) * (1.0f / 256.0f);
  __syncthreads();
  float dv = v - mean;
  float s2 = dv * dv;
  #pragma unroll
  for (int off = 1; off < 64; off <<= 1) s2 += __shfl_xor(s2, off);
  if ((tid & 63) == 0) red[tid >> 6] = s2;
  __syncthreads();
  float var = (red[0] + red[1] + red[2] + red[3]) * (1.0f / 256.0f);
  float o = dv / sqrtf(var + 1e-5f) * lng[tid] + lnb[tid];
  out[(long)r * DM + tid] = o;
  outb[(long)r * DM + tid] = f2bf(o);
}

// ============ sg (mean of qe rows 4096..4100) + permuted s_corr ============
__global__ __launch_bounds__(256) void scorr_kernel(
    const float* __restrict__ qe, const float* __restrict__ whh,
    float* __restrict__ sg, float* __restrict__ s_corr_perm)
{
  __shared__ float sgS[DM];
  int tid = threadIdx.x;
  {
    float v = 0.f;
    #pragma unroll
    for (int r = 0; r < F_SUP; ++r) v += qe[(long)(BQ + r) * DM + tid];
    v *= (1.0f / (float)F_SUP);
    sgS[tid] = v;
    if (blockIdx.x == 0) sg[tid] = v;
  }
  __syncthreads();
  int wave = tid >> 6, lane = tid & 63;
  int n = blockIdx.x * 4 + wave;   // orig row 0..2047
  float4 w = *(const float4*)(whh + (long)n * LH + DM + lane * 4);
  float4 s = *(const float4*)&sgS[lane * 4];
  float d = w.x*s.x + w.y*s.y + w.z*s.z + w.w*s.w;
  #pragma unroll
  for (int off = 1; off < 64; off <<= 1) d += __shfl_xor(d, off);
  if (lane == 0) {
    int g = n >> 9, uu = n & 511;
    int p = (uu >> 5) * 128 + ((uu >> 4) & 1) * 64 + g * 16 + (uu & 15);
    s_corr_perm[p] = d;
  }
}

// ============ final dot (bf16 h) ============
__global__ __launch_bounds__(256) void final_dot_kernel(
    const u16* __restrict__ h, const float* __restrict__ sg, float* __restrict__ out)
{
  __shared__ float red[4];
  int m = blockIdx.x, tid = threadIdx.x;
  float v = bf2f(h[(long)m * DM + tid]) * sg[tid];
  #pragma unroll
  for (int off = 1; off < 64; off <<= 1) v += __shfl_xor(v, off);
  if ((tid & 63) == 0) red[tid >> 6] = v;
  __syncthreads();
  if (tid == 0) out[m] = red[0] + red[1] + red[2] + red[3];
}

extern "C" void kernel_launch(void* const* d_in, const int* in_sizes, int n_in,
                              void* d_out, int out_size, void* d_ws, size_t ws_size,
                              hipStream_t stream)
{
  const int*   query    = (const int*)  d_in[0];
  const int*   support  = (const int*)  d_in[1];
  const int*   q_l1     = (const int*)  d_in[2];
  const int*   q_deg_l  = (const int*)  d_in[3];
  const int*   q_r1     = (const int*)  d_in[4];
  const int*   q_deg_r  = (const int*)  d_in[5];
  const int*   s_l1     = (const int*)  d_in[6];
  const int*   s_deg_l  = (const int*)  d_in[7];
  const int*   s_r1     = (const int*)  d_in[8];
  const int*   s_deg_r  = (const int*)  d_in[9];
  const float* symbol_emb = (const float*)d_in[10];
  const float* gcn_w_w  = (const float*)d_in[11];
  const float* gcn_w_b  = (const float*)d_in[12];
  const float* gcn_b    = (const float*)d_in[13];
  const float* g1_w     = (const float*)d_in[14];
  const float* g1_b     = (const float*)d_in[15];
  const float* ln1_g    = (const float*)d_in[16];
  const float* ln1_b    = (const float*)d_in[17];
  const float* g2_w     = (const float*)d_in[18];
  const float* g2_b     = (const float*)d_in[19];
  const float* gate_temp= (const float*)d_in[20];
  const float* se_p1_w  = (const float*)d_in[21];
  const float* se_p1_b  = (const float*)d_in[22];
  const float* se_p2_w  = (const float*)d_in[23];
  const float* se_p2_b  = (const float*)d_in[24];
  const float* se_ln_g  = (const float*)d_in[25];
  const float* se_ln_b  = (const float*)d_in[26];
  const float* w_ih     = (const float*)d_in[27];
  const float* w_hh     = (const float*)d_in[28];
  const float* b_ih     = (const float*)d_in[29];
  const float* b_hh     = (const float*)d_in[30];

  float* ws = (float*)d_ws;
  size_t off = 0;
  float* projF   = ws + off; off += (size_t)MROWS * 128 / 2;      // bf16 proj
  float* idxF    = ws + off; off += (size_t)MROWS * 2;
  float* qv      = ws + off; off += (size_t)MQ * DM;
  float* qe      = ws + off; off += (size_t)MQ * DM;
  float* qv_bfF  = ws + off; off += (size_t)MQ * DM / 2;
  float* qe_bfF  = ws + off; off += (size_t)MQ * DM / 2;
  float* h1bF    = ws + off; off += (size_t)MQ * DI / 2;
  float* H2      = ws + off; off += (size_t)MQ * DM;
  float* gqbF    = ws + off; off += (size_t)BQ * NG / 2;          // fragment-order gates (bf16)
  float* cstate  = ws + off; off += (size_t)BQ * LH;              // fragment-order c (fp32)
  float* hbf0F   = ws + off; off += (size_t)BQ * DM / 2;
  float* hbf1F   = ws + off; off += (size_t)BQ * DM / 2;
  float* p1bF    = ws + off; off += 131072 / 2;
  float* p2bF    = ws + off; off += 131072 / 2;
  float* gcnbF   = ws + off; off += 32768 / 2;
  float* wihbF   = ws + off; off += 524288 / 2;
  float* whhbF   = ws + off; off += 524288 / 2;
  float* bihh    = ws + off; off += 2048;
  float* sg      = ws + off; off += 256;
  float* s_corr  = ws + off; off += 2048;
  float* metaF   = ws + off; off += 8448;

  u16* proj   = (u16*)projF;
  int* idxA   = (int*)idxF;
  u16* qv_bf  = (u16*)qv_bfF;
  u16* qe_bf  = (u16*)qe_bfF;
  u16* H1_bf  = (u16*)h1bF;
  u16* gq_fr  = (u16*)gqbF;
  u16* hbf0   = (u16*)hbf0F;
  u16* hbf1   = (u16*)hbf1F;
  u16* p1b    = (u16*)p1bF;
  u16* p2b    = (u16*)p2bF;
  u16* gcnb   = (u16*)gcnbF;
  u16* wihb   = (u16*)wihbF;
  u16* whhb   = (u16*)whhbF;
  int* meta   = (int*)metaF;

  // 0. weight casts / permutes
  prep_cast<<<5256, 256, 0, stream>>>(se_p1_w, se_p2_w, gcn_w_w, w_ih, w_hh, b_ih, b_hh,
                                      p1b, p2b, gcnb, wihb, whhb, bihh);

  // 1. gather + top-k -> selected ids
  nbr_topk_kernel<<<2 * BQ + 2 * F_SUP, 256, 0, stream>>>(
      query, support, q_l1, q_r1, s_l1, s_r1, symbol_emb, idxA, meta);

  // 2. proj = emb[idx] @ gcn_w^T   (M=82048, N=128, K=256), LDS-free gather GEMM
  proj_gather_gemm<<<MROWS / 128, 256, 0, stream>>>(idxA, symbol_emb, gcnb, proj);

  // 3. leaky/sum + gate MLP + tanh -> qv rows 0..4100 (query + support)
  nbr_post_kernel<<<2 * BQ + 2 * F_SUP, 128, 0, stream>>>(
      query, support, q_deg_l, q_deg_r, s_deg_l, s_deg_r, symbol_emb,
      proj, meta, gcn_w_b, gcn_b, g1_w, g1_b, ln1_g, ln1_b, g2_w, g2_b, gate_temp,
      qv, qv_bf);

  // 4. encoder (query + 5 support rows ride along)
  mfma_gemm<256><<<(MQ / 128) * (DI / 128), 256, 0, stream>>>(qv_bf, 256, p1b, 256, DI,
      nullptr, H1_bf, se_p1_b, nullptr, nullptr, 1, 0, nullptr, nullptr, nullptr);
  mfma_gemm<512><<<(MQ / 128) * (DM / 128), 256, 0, stream>>>(H1_bf, 512, p2b, 512, DM,
      H2, nullptr, se_p2_b, nullptr, nullptr, 0, 0, nullptr, nullptr, nullptr);
  ln_residual_kernel<<<BQ + F_SUP, 256, 0, stream>>>(H2, qv, se_ln_g, se_ln_b, qe, qe_bf);

  // 5. support_g + permuted s_corr
  scorr_kernel<<<512, 256, 0, stream>>>(qe, w_hh, sg, s_corr);

  // 6. gq = qe@w_ih_perm^T + (b_ih+b_hh); fused LSTM step 1; gates stored fragment-order
  mfma_gemm<256><<<(BQ / 128) * (NG / 128), 256, 0, stream>>>(qe_bf, 256, wihb, 256, NG,
      nullptr, nullptr, bihh, nullptr, gq_fr, 0, 2, cstate, qe, hbf0);

  // 7. steps 2..4: fused GEMM + in-thread LSTM epilogue (h ping-pong)
  mfma_gemm<256><<<(BQ / 128) * (NG / 128), 256, 0, stream>>>(hbf0, 256, whhb, 256, NG,
      nullptr, nullptr, s_corr, gq_fr, nullptr, 0, 1, cstate, qe, hbf1);
  mfma_gemm<256><<<(BQ / 128) * (NG / 128), 256, 0, stream>>>(hbf1, 256, whhb, 256, NG,
      nullptr, nullptr, s_corr, gq_fr, nullptr, 0, 1, cstate, qe, hbf0);
  mfma_gemm<256><<<(BQ / 128) * (NG / 128), 256, 0, stream>>>(hbf0, 256, whhb, 256, NG,
      nullptr, nullptr, s_corr, gq_fr, nullptr, 0, 1, cstate, qe, hbf1);

  // 8. out[m] = dot(h[m], support_g)
  final_dot_kernel<<<BQ, 256, 0, stream>>>(hbf1, sg, (float*)d_out);
}

// Round 7
// 472.163 us; speedup vs baseline: 1.0574x; 1.0574x over previous
//
#include <hip/hip_runtime.h>
#include <math.h>

#define BQ 4096
#define F_SUP 5
#define MAXK 64
#define ED 128
#define DM 256
#define DI 512
#define LH 512
#define NG 2048
#define PADX 200000
#define KNB 10
#define MQ 4224               // 4101 rows padded to 33*128

typedef unsigned short u16;
typedef __attribute__((ext_vector_type(8))) short short8;
typedef __attribute__((ext_vector_type(4))) float floatx4;

__device__ __forceinline__ float sigf(float x) { return 1.0f / (1.0f + __expf(-x)); }
__device__ __forceinline__ float tanh_fast(float x) {
  float a = fabsf(x);
  float e = __expf(-2.0f * a);
  float t = (1.0f - e) / (1.0f + e);
  return copysignf(t, x);
}
__device__ __forceinline__ u16 f2bf(float f) {
  unsigned u = __float_as_uint(f);
  unsigned r = (u + 0x7FFFu + ((u >> 16) & 1u)) >> 16;
  return (u16)r;
}
__device__ __forceinline__ float bf2f(u16 u) {
  return __uint_as_float(((unsigned)u) << 16);
}
__device__ __forceinline__ void gl2lds16(const void* g, void* l) {
  __builtin_amdgcn_global_load_lds(
      (const __attribute__((address_space(1))) void*)g,
      (__attribute__((address_space(3))) void*)l, 16, 0, 0);
}

// ============ fused neighbor encoder: sims + top-k + proj MFMA + gate MLP + tanh ============
// one block per (row, side); 8202 blocks
__global__ __launch_bounds__(256) void nbr_fused_kernel(
    const int* __restrict__ query, const int* __restrict__ support,
    const int* __restrict__ q_l1, const int* __restrict__ q_deg_l,
    const int* __restrict__ q_r1, const int* __restrict__ q_deg_r,
    const int* __restrict__ s_l1, const int* __restrict__ s_deg_l,
    const int* __restrict__ s_r1, const int* __restrict__ s_deg_r,
    const float* __restrict__ emb, const u16* __restrict__ gcnb,
    const float* __restrict__ gcn_w_b, const float* __restrict__ gcn_b,
    const float* __restrict__ g1_w, const float* __restrict__ g1_b,
    const float* __restrict__ ln1_g, const float* __restrict__ ln1_b,
    const float* __restrict__ g2_w, const float* __restrict__ g2_b,
    const float* __restrict__ gate_temp,
    float* __restrict__ qv, u16* __restrict__ qv_bf)
{
  __shared__ int relS[64], entS[64];
  __shared__ __align__(16) float sE[128];
  __shared__ float simS[64];
  __shared__ int selS[16];
  __shared__ int cntS;
  __shared__ float nsS, gateS;
  __shared__ __align__(16) u16 As[16 * 32 * 8];   // [kk][chunk*4+oct'] * 8 bf16 = 8 KB
  __shared__ __align__(16) float aggS[128];

  int tid = threadIdx.x;
  int b = blockIdx.x;
  const int* conn; int self_id, deg, row, colb;
  if (b < BQ)              { int i = b;              conn = q_l1 + i*(MAXK*2); deg = q_deg_l[i]; self_id = query[2*i];     row = i;      colb = 0;  }
  else if (b < 2*BQ)       { int i = b - BQ;         conn = q_r1 + i*(MAXK*2); deg = q_deg_r[i]; self_id = query[2*i+1];   row = i;      colb = ED; }
  else if (b < 2*BQ+F_SUP) { int i = b - 2*BQ;       conn = s_l1 + i*(MAXK*2); deg = s_deg_l[i]; self_id = support[2*i];   row = BQ + i; colb = 0;  }
  else                     { int i = b - 2*BQ-F_SUP; conn = s_r1 + i*(MAXK*2); deg = s_deg_r[i]; self_id = support[2*i+1]; row = BQ + i; colb = ED; }

  if (tid < 128) {
    int v = conn[tid];
    if (tid & 1) entS[tid >> 1] = v; else relS[tid >> 1] = v;
    sE[tid] = emb[(long)self_id * ED + tid];
  }
  __syncthreads();
  if (tid < 64) {
    float v = sE[tid]*sE[tid] + sE[tid+64]*sE[tid+64];
    #pragma unroll
    for (int off = 1; off < 64; off <<= 1) v += __shfl_xor(v, off);
    if (tid == 0) nsS = fmaxf(sqrtf(v), 1e-12f);
  }
  __syncthreads();

  // sims: 4 lanes per k
  {
    int k = tid >> 2, part = tid & 3;
    const float* er = emb + (long)entS[k] * ED + part * 32;
    const float* sr = &sE[part * 32];
    float dot = 0.f, sq = 0.f;
    #pragma unroll
    for (int j = 0; j < 32; j += 4) {
      float4 e = *(const float4*)(er + j);
      float4 s = *(const float4*)(sr + j);
      dot += e.x*s.x + e.y*s.y + e.z*s.z + e.w*s.w;
      sq  += e.x*e.x + e.y*e.y + e.z*e.z + e.w*e.w;
    }
    dot += __shfl_xor(dot, 1); dot += __shfl_xor(dot, 2);
    sq  += __shfl_xor(sq, 1);  sq  += __shfl_xor(sq, 2);
    if (part == 0) {
      float ne = fmaxf(sqrtf(sq), 1e-12f);
      float sim = dot / (nsS * ne);
      if (relS[k] == PADX) sim -= 1e9f;
      simS[k] = sim;
    }
  }
  __syncthreads();

  // exact top-10 (rank), then collect valid selected
  if (tid < 64) {
    float mys = simS[tid];
    int rank = 0;
    #pragma unroll
    for (int j = 0; j < 64; ++j) {
      float s = simS[j];
      rank += ((s > mys) || (s == mys && j < tid)) ? 1 : 0;
    }
    bool val = (rank < KNB) && (relS[tid] != PADX);
    unsigned long long vm = __ballot(val ? 1 : 0);
    if (val) {
      int pos = __popcll(vm & ((1ull << tid) - 1ull));
      selS[pos] = tid;
    }
    if (tid == 0) cntS = __popcll(vm);
  }
  __syncthreads();
  int cnt = cntS;
  float denom = fmaxf((float)cnt, 1.0f);

  // stage A = [kk<16][256] bf16 (cols 0..127 rel emb, 128..255 ent emb), XOR-swizzled octets
  #pragma unroll
  for (int t = 0; t < 2; ++t) {
    int idx = t * 256 + tid;          // 0..511
    int kk = idx >> 5;                // 0..15
    int oct = idx & 31;               // 8-elem group within 256 cols
    int c0 = oct >> 2, o = oct & 3;
    int op = o ^ (kk & 3);
    u16* dst = &As[(size_t)((kk * 32) + (c0 * 4) + op) * 8];
    if (kk < cnt) {
      int k = selS[kk];
      int id = (oct < 16) ? relS[k] : entS[k];
      int coff = (oct * 8) & 127;
      const float* src = emb + (long)id * ED + coff;
      float4 f0 = *(const float4*)(src);
      float4 f1 = *(const float4*)(src + 4);
      dst[0]=f2bf(f0.x); dst[1]=f2bf(f0.y); dst[2]=f2bf(f0.z); dst[3]=f2bf(f0.w);
      dst[4]=f2bf(f1.x); dst[5]=f2bf(f1.y); dst[6]=f2bf(f1.z); dst[7]=f2bf(f1.w);
    } else {
      *(short8*)dst = short8{0,0,0,0,0,0,0,0};
    }
  }
  __syncthreads();

  // proj MFMA: M=16 (kk), N=128 (4 waves x 2 tiles), K=256; B direct from L2-hot gcnb
  {
    int lane = tid & 63, wave = tid >> 6;
    int col = lane & 15, quad = lane >> 4;
    floatx4 acc[2];
    acc[0] = floatx4{0.f,0.f,0.f,0.f};
    acc[1] = floatx4{0.f,0.f,0.f,0.f};
    #pragma unroll
    for (int c0 = 0; c0 < 8; ++c0) {
      short8 a = *(const short8*)&As[(size_t)((col * 32) + c0 * 4 + (quad ^ (col & 3))) * 8];
      #pragma unroll
      for (int jt = 0; jt < 2; ++jt) {
        const u16* bp = gcnb + (long)(wave * 32 + jt * 16 + col) * 256 + c0 * 32 + quad * 8;
        short8 bfr = *(const short8*)bp;
        acc[jt] = __builtin_amdgcn_mfma_f32_16x16x32_bf16(a, bfr, acc[jt], 0, 0, 0);
      }
    }
    #pragma unroll
    for (int jt = 0; jt < 2; ++jt) {
      int n = wave * 32 + jt * 16 + col;
      float bsum = gcn_w_b[n] + gcn_b[n];
      float v = 0.f;
      #pragma unroll
      for (int r = 0; r < 4; ++r) {
        int kk = quad * 4 + r;
        float z = acc[jt][r] + bsum;
        z = (z >= 0.f) ? z : 0.01f * z;
        v += (kk < cnt) ? z : 0.f;
      }
      v += __shfl_xor(v, 16);
      v += __shfl_xor(v, 32);
      if (quad == 0) aggS[n] = v / denom;
    }
  }
  __syncthreads();

  // gate MLP: 128->64, LN, relu, ->1
  if (tid < 64) {
    int e = tid;
    const float4* g1r = (const float4*)(g1_w + e * ED);
    float y = g1_b[e];
    #pragma unroll 8
    for (int j = 0; j < 32; ++j) {
      float4 w = g1r[j];
      float4 a = *(const float4*)&aggS[j * 4];
      y += w.x*a.x + w.y*a.y + w.z*a.z + w.w*a.w;
    }
    float s = y;
    #pragma unroll
    for (int off = 1; off < 64; off <<= 1) s += __shfl_xor(s, off);
    float mean = s * (1.0f / 64.0f);
    float dv = y - mean;
    float s2 = dv * dv;
    #pragma unroll
    for (int off = 1; off < 64; off <<= 1) s2 += __shfl_xor(s2, off);
    float var = s2 * (1.0f / 64.0f);
    float hv = dv / sqrtf(var + 1e-5f) * ln1_g[e] + ln1_b[e];
    hv = fmaxf(hv, 0.f);
    float lp = hv * g2_w[e];
    #pragma unroll
    for (int off = 1; off < 64; off <<= 1) lp += __shfl_xor(lp, off);
    if (e == 0) {
      float logit = lp + g2_b[0];
      float temp = fminf(fmaxf(gate_temp[0], 0.1f), 5.0f);
      float gate = 1.0f / (1.0f + expf(-logit / temp));
      if (deg <= 0) gate = 0.f;
      gateS = gate;
    }
  }
  __syncthreads();
  if (tid < 128) {
    float o = tanhf(sE[tid] + gateS * aggS[tid]);
    qv[(long)row * DM + colb + tid] = o;
    qv_bf[(long)row * DM + colb + tid] = f2bf(o);
  }
}

// ============ double-buffered LDS MFMA bf16 GEMM. lstm_mode: 0 none, 1 step, 2 first step.
// LSTM modes: j=gate permutation (gate=j, unit u=bn*32+wnx*16+col); gq/cstate in
// C-fragment order (fb=(blk*4+wave)*64+lane).
template<int K>
__global__ __launch_bounds__(256) void mfma_gemm(
    const u16* __restrict__ A, int lda,
    const u16* __restrict__ W, int ldw,
    int N,
    float* __restrict__ Cout, u16* __restrict__ Cbf,
    const float* __restrict__ bias0,
    const u16* __restrict__ gqin,       // lstm_mode==1: fragment-order gates input
    u16* __restrict__ gqout,            // lstm_mode==2: fragment-order gates output
    int relu, int lstm_mode,
    float* __restrict__ cstate, const float* __restrict__ qe,
    u16* __restrict__ hbf)
{
  __shared__ u16 As[2][128 * 32];
  __shared__ u16 Bs[2][128 * 32];
  int tid = threadIdx.x;
  int nb = N >> 7;
  int bn = blockIdx.x % nb, bm = blockIdx.x / nb;
  int lane = tid & 63, wave = tid >> 6;
  int wm = (wave & 1) * 64, wn = (wave >> 1) * 64;
  int col = lane & 15, quad = lane >> 4;

  // ---- epilogue input prefetch (latency hides under the K-loop) ----
  u16 gqa[64]; float cpv[16]; float qev[16]; float scv[4];
  int u = 0; long fb = 0;
  if (lstm_mode) {
    u = bn * 32 + (wave >> 1) * 16 + col;
    fb = ((long)blockIdx.x * 4 + wave) * 64 + lane;
    #pragma unroll
    for (int j = 0; j < 4; ++j)
      scv[j] = bias0[bn * 128 + (wave >> 1) * 64 + j * 16 + col];
    if (lstm_mode == 1) {
      const short8* gp = (const short8*)(gqin + fb * 64);
      #pragma unroll
      for (int t = 0; t < 8; ++t) *(short8*)&gqa[t * 8] = gp[t];
      const float4* cp = (const float4*)(cstate + fb * 16);
      #pragma unroll
      for (int t = 0; t < 4; ++t) *(float4*)&cpv[t * 4] = cp[t];
    }
    if (u < DM) {
      #pragma unroll
      for (int i = 0; i < 4; ++i)
        #pragma unroll
        for (int r = 0; r < 4; ++r) {
          int m = bm * 128 + (wave & 1) * 64 + i * 16 + quad * 4 + r;
          qev[i * 4 + r] = qe[(long)m * DM + u];
        }
    }
  }

  // staging helper indices
  int sr = tid >> 1;                 // unused placeholder to keep regs low
  (void)sr;

  floatx4 acc[4][4];
  #pragma unroll
  for (int i = 0; i < 4; ++i)
    #pragma unroll
    for (int j = 0; j < 4; ++j) { floatx4 z = {0.f,0.f,0.f,0.f}; acc[i][j] = z; }

  // issue first tile
  {
    #pragma unroll
    for (int t = 0; t < 2; ++t) {
      int c = t * 256 + tid;
      int r = c >> 2, o = c & 3;
      int og = o ^ (r & 3);
      gl2lds16(A + (long)(bm * 128 + r) * lda + 0 + og * 8, &As[0][(size_t)c * 8]);
      gl2lds16(W + (long)(bn * 128 + r) * ldw + 0 + og * 8, &Bs[0][(size_t)c * 8]);
    }
  }

  for (int k0 = 0; k0 < K; k0 += 32) {
    int cur = (k0 >> 5) & 1;
    __syncthreads();                         // tile `cur` resident; prev buffer free
    if (k0 + 32 < K) {
      int nxt = cur ^ 1;
      #pragma unroll
      for (int t = 0; t < 2; ++t) {
        int c = t * 256 + tid;
        int r = c >> 2, o = c & 3;
        int og = o ^ (r & 3);
        gl2lds16(A + (long)(bm * 128 + r) * lda + (k0 + 32) + og * 8, &As[nxt][(size_t)c * 8]);
        gl2lds16(W + (long)(bn * 128 + r) * ldw + (k0 + 32) + og * 8, &Bs[nxt][(size_t)c * 8]);
      }
    }
    short8 af[4], bfr[4];
    #pragma unroll
    for (int i = 0; i < 4; ++i) {
      int ra = wm + i * 16 + col;
      af[i] = *(const short8*)&As[cur][(size_t)(ra * 4 + (quad ^ (ra & 3))) * 8];
      int rb = wn + i * 16 + col;
      bfr[i] = *(const short8*)&Bs[cur][(size_t)(rb * 4 + (quad ^ (rb & 3))) * 8];
    }
    #pragma unroll
    for (int i = 0; i < 4; ++i)
      #pragma unroll
      for (int j = 0; j < 4; ++j)
        acc[i][j] = __builtin_amdgcn_mfma_f32_16x16x32_bf16(af[i], bfr[j], acc[i][j], 0, 0, 0);
  }

  if (lstm_mode) {
    float cnew[16];
    #pragma unroll
    for (int i = 0; i < 4; ++i) {
      #pragma unroll
      for (int r = 0; r < 4; ++r) {
        float gI = acc[i][0][r] + scv[0];
        float gF = acc[i][1][r] + scv[1];
        float gG = acc[i][2][r] + scv[2];
        float gO = acc[i][3][r] + scv[3];
        if (lstm_mode == 1) {
          gI += bf2f(gqa[(i * 4 + 0) * 4 + r]);
          gF += bf2f(gqa[(i * 4 + 1) * 4 + r]);
          gG += bf2f(gqa[(i * 4 + 2) * 4 + r]);
          gO += bf2f(gqa[(i * 4 + 3) * 4 + r]);
        }
        float cp = (lstm_mode == 2) ? 0.f : cpv[i * 4 + r];
        float cn = sigf(gF) * cp + sigf(gI) * tanh_fast(gG);
        cnew[i * 4 + r] = cn;
        if (u < DM) {
          int m = bm * 128 + (wave & 1) * 64 + i * 16 + quad * 4 + r;
          hbf[(long)m * DM + u] = f2bf(qev[i * 4 + r] + sigf(gO) * tanh_fast(cn));
        }
      }
    }
    {
      float4* cp = (float4*)(cstate + fb * 16);
      #pragma unroll
      for (int t = 0; t < 4; ++t) cp[t] = *(float4*)&cnew[t * 4];
    }
    if (lstm_mode == 2) {
      u16 ga[64];
      #pragma unroll
      for (int i = 0; i < 4; ++i)
        #pragma unroll
        for (int j = 0; j < 4; ++j)
          #pragma unroll
          for (int r = 0; r < 4; ++r)
            ga[(i * 4 + j) * 4 + r] = f2bf(acc[i][j][r] + scv[j]);
      short8* gp = (short8*)(gqout + fb * 64);
      #pragma unroll
      for (int t = 0; t < 8; ++t) gp[t] = *(short8*)&ga[t * 8];
    }
  } else {
    int gm0 = bm * 128 + wm + quad * 4;
    int gn0 = bn * 128 + wn + col;
    #pragma unroll
    for (int i = 0; i < 4; ++i) {
      #pragma unroll
      for (int j = 0; j < 4; ++j) {
        int n = gn0 + j * 16;
        #pragma unroll
        for (int r = 0; r < 4; ++r) {
          int m = gm0 + i * 16 + r;
          float v = acc[i][j][r];
          if (bias0) v += bias0[n];
          if (relu) v = fmaxf(v, 0.f);
          if (Cout) Cout[(long)m * N + n] = v;
          if (Cbf)  Cbf[(long)m * N + n] = f2bf(v);
        }
      }
    }
  }
}

// ============ weight casts + j=gate permuted layouts ============
// position p in [0,2048): g=(p>>4)&3, u=(p>>7)*32+((p>>6)&1)*16+(p&15), orig row n=g*512+u
__global__ void prep_cast(
    const float* __restrict__ p1, const float* __restrict__ p2,
    const float* __restrict__ gcnw, const float* __restrict__ wih,
    const float* __restrict__ whh, const float* __restrict__ bih,
    const float* __restrict__ bhh,
    u16* __restrict__ p1b, u16* __restrict__ p2b, u16* __restrict__ gcnb,
    u16* __restrict__ wihb, u16* __restrict__ whhb, float* __restrict__ bihh)
{
  int gid = blockIdx.x * 256 + threadIdx.x;
  if (gid < 131072) { p1b[gid] = f2bf(p1[gid]); }
  else if (gid < 262144) { int i = gid - 131072; p2b[i] = f2bf(p2[i]); }
  else if (gid < 294912) { int i = gid - 262144; gcnb[i] = f2bf(gcnw[i]); }
  else if (gid < 819200) {
    int i = gid - 294912; int p = i >> 8, k = i & 255;
    int g = (p >> 4) & 3, uu = (p >> 7) * 32 + ((p >> 6) & 1) * 16 + (p & 15);
    int n = g * 512 + uu;
    wihb[i] = f2bf(wih[(long)n * DM + k]);
  } else if (gid < 1343488) {
    int i = gid - 819200; int p = i >> 8, k = i & 255;
    int g = (p >> 4) & 3, uu = (p >> 7) * 32 + ((p >> 6) & 1) * 16 + (p & 15);
    int n = g * 512 + uu;
    whhb[i] = f2bf(whh[(long)n * LH + k]);
  } else if (gid < 1345536) {
    int p = gid - 1343488;
    int g = (p >> 4) & 3, uu = (p >> 7) * 32 + ((p >> 6) & 1) * 16 + (p & 15);
    int n = g * 512 + uu;
    bihh[p] = bih[n] + bhh[n];
  }
}

// ============ residual layernorm -> qe (fp32 + bf16), rows 0..4100 ============
__global__ __launch_bounds__(256) void ln_residual_kernel(
    const float* __restrict__ h2buf, const float* __restrict__ xbuf,
    const float* __restrict__ lng, const float* __restrict__ lnb,
    float* __restrict__ out, u16* __restrict__ outb)
{
  __shared__ float red[4];
  int r = blockIdx.x, tid = threadIdx.x;
  float v = h2buf[(long)r * DM + tid] + xbuf[(long)r * DM + tid];
  float s = v;
  #pragma unroll
  for (int off = 1; off < 64; off <<= 1) s += __shfl_xor(s, off);
  if ((tid & 63) == 0) red[tid >> 6] = s;
  __syncthreads();
  float mean = (red[0] + red[1] + red[2] + red[3]) * (1.0f / 256.0f);
  __syncthreads();
  float dv = v - mean;
  float s2 = dv * dv;
  #pragma unroll
  for (int off = 1; off < 64; off <<= 1) s2 += __shfl_xor(s2, off);
  if ((tid & 63) == 0) red[tid >> 6] = s2;
  __syncthreads();
  float var = (red[0] + red[1] + red[2] + red[3]) * (1.0f / 256.0f);
  float o = dv / sqrtf(var + 1e-5f) * lng[tid] + lnb[tid];
  out[(long)r * DM + tid] = o;
  outb[(long)r * DM + tid] = f2bf(o);
}

// ============ sg (mean of qe rows 4096..4100) + permuted s_corr ============
__global__ __launch_bounds__(256) void scorr_kernel(
    const float* __restrict__ qe, const float* __restrict__ whh,
    float* __restrict__ sg, float* __restrict__ s_corr_perm)
{
  __shared__ float sgS[DM];
  int tid = threadIdx.x;
  {
    float v = 0.f;
    #pragma unroll
    for (int r = 0; r < F_SUP; ++r) v += qe[(long)(BQ + r) * DM + tid];
    v *= (1.0f / (float)F_SUP);
    sgS[tid] = v;
    if (blockIdx.x == 0) sg[tid] = v;
  }
  __syncthreads();
  int wave = tid >> 6, lane = tid & 63;
  int n = blockIdx.x * 4 + wave;   // orig row 0..2047
  float4 w = *(const float4*)(whh + (long)n * LH + DM + lane * 4);
  float4 s = *(const float4*)&sgS[lane * 4];
  float d = w.x*s.x + w.y*s.y + w.z*s.z + w.w*s.w;
  #pragma unroll
  for (int off = 1; off < 64; off <<= 1) d += __shfl_xor(d, off);
  if (lane == 0) {
    int g = n >> 9, uu = n & 511;
    int p = (uu >> 5) * 128 + ((uu >> 4) & 1) * 64 + g * 16 + (uu & 15);
    s_corr_perm[p] = d;
  }
}

// ============ final dot (bf16 h) ============
__global__ __launch_bounds__(256) void final_dot_kernel(
    const u16* __restrict__ h, const float* __restrict__ sg, float* __restrict__ out)
{
  __shared__ float red[4];
  int m = blockIdx.x, tid = threadIdx.x;
  float v = bf2f(h[(long)m * DM + tid]) * sg[tid];
  #pragma unroll
  for (int off = 1; off < 64; off <<= 1) v += __shfl_xor(v, off);
  if ((tid & 63) == 0) red[tid >> 6] = v;
  __syncthreads();
  if (tid == 0) out[m] = red[0] + red[1] + red[2] + red[3];
}

extern "C" void kernel_launch(void* const* d_in, const int* in_sizes, int n_in,
                              void* d_out, int out_size, void* d_ws, size_t ws_size,
                              hipStream_t stream)
{
  const int*   query    = (const int*)  d_in[0];
  const int*   support  = (const int*)  d_in[1];
  const int*   q_l1     = (const int*)  d_in[2];
  const int*   q_deg_l  = (const int*)  d_in[3];
  const int*   q_r1     = (const int*)  d_in[4];
  const int*   q_deg_r  = (const int*)  d_in[5];
  const int*   s_l1     = (const int*)  d_in[6];
  const int*   s_deg_l  = (const int*)  d_in[7];
  const int*   s_r1     = (const int*)  d_in[8];
  const int*   s_deg_r  = (const int*)  d_in[9];
  const float* symbol_emb = (const float*)d_in[10];
  const float* gcn_w_w  = (const float*)d_in[11];
  const float* gcn_w_b  = (const float*)d_in[12];
  const float* gcn_b    = (const float*)d_in[13];
  const float* g1_w     = (const float*)d_in[14];
  const float* g1_b     = (const float*)d_in[15];
  const float* ln1_g    = (const float*)d_in[16];
  const float* ln1_b    = (const float*)d_in[17];
  const float* g2_w     = (const float*)d_in[18];
  const float* g2_b     = (const float*)d_in[19];
  const float* gate_temp= (const float*)d_in[20];
  const float* se_p1_w  = (const float*)d_in[21];
  const float* se_p1_b  = (const float*)d_in[22];
  const float* se_p2_w  = (const float*)d_in[23];
  const float* se_p2_b  = (const float*)d_in[24];
  const float* se_ln_g  = (const float*)d_in[25];
  const float* se_ln_b  = (const float*)d_in[26];
  const float* w_ih     = (const float*)d_in[27];
  const float* w_hh     = (const float*)d_in[28];
  const float* b_ih     = (const float*)d_in[29];
  const float* b_hh     = (const float*)d_in[30];

  float* ws = (float*)d_ws;
  size_t off = 0;
  float* qv      = ws + off; off += (size_t)MQ * DM;
  float* qe      = ws + off; off += (size_t)MQ * DM;
  float* qv_bfF  = ws + off; off += (size_t)MQ * DM / 2;
  float* qe_bfF  = ws + off; off += (size_t)MQ * DM / 2;
  float* h1bF    = ws + off; off += (size_t)MQ * DI / 2;
  float* H2      = ws + off; off += (size_t)MQ * DM;
  float* gqbF    = ws + off; off += (size_t)BQ * NG / 2;          // fragment-order gates (bf16)
  float* cstate  = ws + off; off += (size_t)BQ * LH;              // fragment-order c (fp32)
  float* hbf0F   = ws + off; off += (size_t)BQ * DM / 2;
  float* hbf1F   = ws + off; off += (size_t)BQ * DM / 2;
  float* p1bF    = ws + off; off += 131072 / 2;
  float* p2bF    = ws + off; off += 131072 / 2;
  float* gcnbF   = ws + off; off += 32768 / 2;
  float* wihbF   = ws + off; off += 524288 / 2;
  float* whhbF   = ws + off; off += 524288 / 2;
  float* bihh    = ws + off; off += 2048;
  float* sg      = ws + off; off += 256;
  float* s_corr  = ws + off; off += 2048;

  u16* qv_bf  = (u16*)qv_bfF;
  u16* qe_bf  = (u16*)qe_bfF;
  u16* H1_bf  = (u16*)h1bF;
  u16* gq_fr  = (u16*)gqbF;
  u16* hbf0   = (u16*)hbf0F;
  u16* hbf1   = (u16*)hbf1F;
  u16* p1b    = (u16*)p1bF;
  u16* p2b    = (u16*)p2bF;
  u16* gcnb   = (u16*)gcnbF;
  u16* wihb   = (u16*)wihbF;
  u16* whhb   = (u16*)whhbF;

  // 0. weight casts / permutes
  prep_cast<<<5256, 256, 0, stream>>>(se_p1_w, se_p2_w, gcn_w_w, w_ih, w_hh, b_ih, b_hh,
                                      p1b, p2b, gcnb, wihb, whhb, bihh);

  // 1. fused neighbor encoder -> qv rows 0..4100 (query + support)
  nbr_fused_kernel<<<2 * BQ + 2 * F_SUP, 256, 0, stream>>>(
      query, support, q_l1, q_deg_l, q_r1, q_deg_r, s_l1, s_deg_l, s_r1, s_deg_r,
      symbol_emb, gcnb, gcn_w_b, gcn_b, g1_w, g1_b, ln1_g, ln1_b, g2_w, g2_b, gate_temp,
      qv, qv_bf);

  // 2. encoder (query + 5 support rows ride along)
  mfma_gemm<256><<<(MQ / 128) * (DI / 128), 256, 0, stream>>>(qv_bf, 256, p1b, 256, DI,
      nullptr, H1_bf, se_p1_b, nullptr, nullptr, 1, 0, nullptr, nullptr, nullptr);
  mfma_gemm<512><<<(MQ / 128) * (DM / 128), 256, 0, stream>>>(H1_bf, 512, p2b, 512, DM,
      H2, nullptr, se_p2_b, nullptr, nullptr, 0, 0, nullptr, nullptr, nullptr);
  ln_residual_kernel<<<BQ + F_SUP, 256, 0, stream>>>(H2, qv, se_ln_g, se_ln_b, qe, qe_bf);

  // 3. support_g + permuted s_corr
  scorr_kernel<<<512, 256, 0, stream>>>(qe, w_hh, sg, s_corr);

  // 4. gq = qe@w_ih_perm^T + (b_ih+b_hh); fused LSTM step 1; gates stored fragment-order
  mfma_gemm<256><<<(BQ / 128) * (NG / 128), 256, 0, stream>>>(qe_bf, 256, wihb, 256, NG,
      nullptr, nullptr, bihh, nullptr, gq_fr, 0, 2, cstate, qe, hbf0);

  // 5. steps 2..4: fused GEMM + in-thread LSTM epilogue (h ping-pong)
  mfma_gemm<256><<<(BQ / 128) * (NG / 128), 256, 0, stream>>>(hbf0, 256, whhb, 256, NG,
      nullptr, nullptr, s_corr, gq_fr, nullptr, 0, 1, cstate, qe, hbf1);
  mfma_gemm<256><<<(BQ / 128) * (NG / 128), 256, 0, stream>>>(hbf1, 256, whhb, 256, NG,
      nullptr, nullptr, s_corr, gq_fr, nullptr, 0, 1, cstate, qe, hbf0);
  mfma_gemm<256><<<(BQ / 128) * (NG / 128), 256, 0, stream>>>(hbf0, 256, whhb, 256, NG,
      nullptr, nullptr, s_corr, gq_fr, nullptr, 0, 1, cstate, qe, hbf1);

  // 6. out[m] = dot(h[m], support_g)
  final_dot_kernel<<<BQ, 256, 0, stream>>>(hbf1, sg, (float*)d_out);
}

// Round 8
// 451.550 us; speedup vs baseline: 1.1057x; 1.0457x over previous
//
#include <hip/hip_runtime.h>
#include <math.h>

#define BQ 4096
#define F_SUP 5
#define MAXK 64
#define ED 128
#define DM 256
#define DI 512
#define LH 512
#define NG 2048
#define PADX 200000
#define KNB 10
#define MROWS 82048           // 8202*10 padded to 641*128
#define MREAL 82020
#define MQ 4224               // 4101 rows padded to 33*128

typedef unsigned short u16;
typedef __attribute__((ext_vector_type(8))) short short8;
typedef __attribute__((ext_vector_type(4))) float floatx4;

__device__ __forceinline__ float sigf(float x) { return 1.0f / (1.0f + __expf(-x)); }
__device__ __forceinline__ float tanh_fast(float x) {
  float a = fabsf(x);
  float e = __expf(-2.0f * a);
  float t = (1.0f - e) / (1.0f + e);
  return copysignf(t, x);
}
__device__ __forceinline__ u16 f2bf(float f) {
  unsigned u = __float_as_uint(f);
  unsigned r = (u + 0x7FFFu + ((u >> 16) & 1u)) >> 16;
  return (u16)r;
}
__device__ __forceinline__ float bf2f(u16 u) {
  return __uint_as_float(((unsigned)u) << 16);
}
__device__ __forceinline__ void gl2lds16(const void* g, void* l) {
  __builtin_amdgcn_global_load_lds(
      (const __attribute__((address_space(1))) void*)g,
      (__attribute__((address_space(3))) void*)l, 16, 0, 0);
}

// ============ phase A: gather + sims + top-k -> selected symbol ids ============
__global__ __launch_bounds__(256) void nbr_topk_kernel(
    const int* __restrict__ query, const int* __restrict__ support,
    const int* __restrict__ q_l1, const int* __restrict__ q_r1,
    const int* __restrict__ s_l1, const int* __restrict__ s_r1,
    const float* __restrict__ emb,
    int* __restrict__ idxA, int* __restrict__ meta)
{
  __shared__ int relS[64], entS[64];
  __shared__ __align__(16) float sE[128];
  __shared__ float simS[64];
  __shared__ int selS[16];
  __shared__ int cntS;
  __shared__ float nsS;

  int tid = threadIdx.x;
  int b = blockIdx.x;
  const int* conn; int self_id;
  if (b < BQ)              { int i = b;              conn = q_l1 + i*(MAXK*2); self_id = query[2*i];   }
  else if (b < 2*BQ)       { int i = b - BQ;         conn = q_r1 + i*(MAXK*2); self_id = query[2*i+1]; }
  else if (b < 2*BQ+F_SUP) { int i = b - 2*BQ;       conn = s_l1 + i*(MAXK*2); self_id = support[2*i]; }
  else                     { int i = b - 2*BQ-F_SUP; conn = s_r1 + i*(MAXK*2); self_id = support[2*i+1]; }

  if (tid < 128) {
    int v = conn[tid];
    if (tid & 1) entS[tid >> 1] = v; else relS[tid >> 1] = v;
    sE[tid] = emb[(long)self_id * ED + tid];
  }
  __syncthreads();
  if (tid < 64) {
    float v = sE[tid]*sE[tid] + sE[tid+64]*sE[tid+64];
    #pragma unroll
    for (int off = 1; off < 64; off <<= 1) v += __shfl_xor(v, off);
    if (tid == 0) nsS = fmaxf(sqrtf(v), 1e-12f);
  }
  __syncthreads();

  {
    int k = tid >> 2, part = tid & 3;
    const float* er = emb + (long)entS[k] * ED + part * 32;
    const float* sr = &sE[part * 32];
    float dot = 0.f, sq = 0.f;
    #pragma unroll
    for (int j = 0; j < 32; j += 4) {
      float4 e = *(const float4*)(er + j);
      float4 s = *(const float4*)(sr + j);
      dot += e.x*s.x + e.y*s.y + e.z*s.z + e.w*s.w;
      sq  += e.x*e.x + e.y*e.y + e.z*e.z + e.w*e.w;
    }
    dot += __shfl_xor(dot, 1); dot += __shfl_xor(dot, 2);
    sq  += __shfl_xor(sq, 1);  sq  += __shfl_xor(sq, 2);
    if (part == 0) {
      float ne = fmaxf(sqrtf(sq), 1e-12f);
      float sim = dot / (nsS * ne);
      if (relS[k] == PADX) sim -= 1e9f;
      simS[k] = sim;
    }
  }
  __syncthreads();

  if (tid < 64) {
    float mys = simS[tid];
    int rank = 0;
    #pragma unroll
    for (int j = 0; j < 64; ++j) {
      float s = simS[j];
      rank += ((s > mys) || (s == mys && j < tid)) ? 1 : 0;
    }
    bool val = (rank < KNB) && (relS[tid] != PADX);
    unsigned long long vm = __ballot(val ? 1 : 0);
    if (val) {
      int pos = __popcll(vm & ((1ull << tid) - 1ull));
      selS[pos] = tid;
    }
    if (tid == 0) { cntS = __popcll(vm); meta[b] = __popcll(vm); }
  }
  __syncthreads();

  int cnt = cntS;
  long base = (long)b * 10;
  if (tid < 2 * KNB) {
    int kk = tid >> 1, h = tid & 1;
    int id = PADX;                                  // PAD row of emb is all zeros
    if (kk < cnt) { int k = selS[kk]; id = h ? entS[k] : relS[k]; }
    idxA[(base + kk) * 2 + h] = id;
  }
  if (b == 0 && tid >= 128 && tid < 128 + 2 * (MROWS - MREAL)) {
    idxA[(long)MREAL * 2 + (tid - 128)] = PADX;     // pad rows -> zero emb row
  }
}

// ============ proj GEMM with fused gather (LDS-staged): proj[M,128] = emb[idx] @ gcn_w^T ============
__global__ __launch_bounds__(256) void proj_gather_gemm(
    const int* __restrict__ idxA, const float* __restrict__ emb,
    const u16* __restrict__ W, u16* __restrict__ proj)
{
  __shared__ u16 As[128 * 32];
  __shared__ u16 Bs[128 * 32];
  __shared__ int idxS[256];
  int tid = threadIdx.x;
  int bm = blockIdx.x;
  idxS[tid] = idxA[bm * 256 + tid];
  int lane = tid & 63, wave = tid >> 6;
  int wm = (wave & 1) * 64, wn = (wave >> 1) * 64;
  int col = lane & 15, quad = lane >> 4;
  int r = tid >> 1, part = tid & 1;

  floatx4 acc[4][4];
  #pragma unroll
  for (int i = 0; i < 4; ++i)
    #pragma unroll
    for (int j = 0; j < 4; ++j) { floatx4 z = {0.f,0.f,0.f,0.f}; acc[i][j] = z; }
  __syncthreads();

  for (int k0 = 0; k0 < 256; k0 += 32) {
    int half = k0 >> 7, koff = k0 & 127;
    #pragma unroll
    for (int t = 0; t < 2; ++t) {
      int c = t * 256 + tid;
      int rb = c >> 2, o = c & 3;
      int og = o ^ (rb & 3);
      gl2lds16(W + (long)rb * 256 + k0 + og * 8, &Bs[(size_t)c * 8]);
    }
    {
      int id = idxS[r * 2 + half];
      const float* src = emb + (long)id * ED + koff + part * 16;
      float4 f0 = *(const float4*)(src);
      float4 f1 = *(const float4*)(src + 4);
      float4 f2 = *(const float4*)(src + 8);
      float4 f3 = *(const float4*)(src + 12);
      short8 s0, s1;
      s0[0]=(short)f2bf(f0.x); s0[1]=(short)f2bf(f0.y); s0[2]=(short)f2bf(f0.z); s0[3]=(short)f2bf(f0.w);
      s0[4]=(short)f2bf(f1.x); s0[5]=(short)f2bf(f1.y); s0[6]=(short)f2bf(f1.z); s0[7]=(short)f2bf(f1.w);
      s1[0]=(short)f2bf(f2.x); s1[1]=(short)f2bf(f2.y); s1[2]=(short)f2bf(f2.z); s1[3]=(short)f2bf(f2.w);
      s1[4]=(short)f2bf(f3.x); s1[5]=(short)f2bf(f3.y); s1[6]=(short)f2bf(f3.z); s1[7]=(short)f2bf(f3.w);
      int o0 = 2 * part, o1 = 2 * part + 1;
      *(short8*)&As[(size_t)(r * 4 + (o0 ^ (r & 3))) * 8] = s0;
      *(short8*)&As[(size_t)(r * 4 + (o1 ^ (r & 3))) * 8] = s1;
    }
    __syncthreads();
    short8 af[4], bfr[4];
    #pragma unroll
    for (int i = 0; i < 4; ++i) {
      int ra = wm + i * 16 + col;
      af[i] = *(const short8*)&As[(size_t)(ra * 4 + (quad ^ (ra & 3))) * 8];
      int rb = wn + i * 16 + col;
      bfr[i] = *(const short8*)&Bs[(size_t)(rb * 4 + (quad ^ (rb & 3))) * 8];
    }
    #pragma unroll
    for (int i = 0; i < 4; ++i)
      #pragma unroll
      for (int j = 0; j < 4; ++j)
        acc[i][j] = __builtin_amdgcn_mfma_f32_16x16x32_bf16(af[i], bfr[j], acc[i][j], 0, 0, 0);
    __syncthreads();
  }
  int gm0 = bm * 128 + wm + quad * 4;
  int gn0 = wn + col;
  #pragma unroll
  for (int i = 0; i < 4; ++i)
    #pragma unroll
    for (int j = 0; j < 4; ++j)
      #pragma unroll
      for (int rr = 0; rr < 4; ++rr)
        proj[(long)(gm0 + i * 16 + rr) * 128 + gn0 + j * 16] = f2bf(acc[i][j][rr]);
}

// ============ phase C: leaky/sum + gate MLP + tanh output ============
__global__ __launch_bounds__(128) void nbr_post_kernel(
    const int* __restrict__ query, const int* __restrict__ support,
    const int* __restrict__ q_deg_l, const int* __restrict__ q_deg_r,
    const int* __restrict__ s_deg_l, const int* __restrict__ s_deg_r,
    const float* __restrict__ emb,
    const u16* __restrict__ proj, const int* __restrict__ meta,
    const float* __restrict__ gcn_w_b, const float* __restrict__ gcn_b,
    const float* __restrict__ g1_w, const float* __restrict__ g1_b,
    const float* __restrict__ ln1_g, const float* __restrict__ ln1_b,
    const float* __restrict__ g2_w, const float* __restrict__ g2_b,
    const float* __restrict__ gate_temp,
    float* __restrict__ qv, u16* __restrict__ qv_bf)
{
  __shared__ __align__(16) float aggS[128];
  __shared__ float sEs[128];
  __shared__ float gateS;
  int tid = threadIdx.x, b = blockIdx.x;
  int deg, self_id, row, colb;
  if (b < BQ)              { int i = b;              deg = q_deg_l[i]; self_id = query[2*i];     row = i;        colb = 0;  }
  else if (b < 2*BQ)       { int i = b - BQ;         deg = q_deg_r[i]; self_id = query[2*i+1];   row = i;        colb = ED; }
  else if (b < 2*BQ+F_SUP) { int i = b - 2*BQ;       deg = s_deg_l[i]; self_id = support[2*i];   row = BQ + i;   colb = 0;  }
  else                     { int i = b - 2*BQ-F_SUP; deg = s_deg_r[i]; self_id = support[2*i+1]; row = BQ + i;   colb = ED; }
  float* outp = qv + (long)row * DM + colb;
  u16*  outpb = qv_bf + (long)row * DM + colb;

  int cnt = meta[b];
  float denom = fmaxf((float)cnt, 1.0f);
  float bsum = gcn_w_b[tid] + gcn_b[tid];
  float agg = 0.f;
  long pbase = (long)b * 10;
  for (int kk = 0; kk < cnt; ++kk) {
    float z = bf2f(proj[(pbase + kk) * 128 + tid]) + bsum;
    z = (z >= 0.f) ? z : 0.01f * z;
    agg += z;
  }
  agg /= denom;
  aggS[tid] = agg;
  sEs[tid] = emb[(long)self_id * ED + tid];
  __syncthreads();

  if (tid < 64) {
    int e = tid;
    const float4* g1r = (const float4*)(g1_w + e * ED);
    float y = g1_b[e];
    #pragma unroll 8
    for (int j = 0; j < 32; ++j) {
      float4 w = g1r[j];
      float4 a = *(const float4*)&aggS[j * 4];
      y += w.x*a.x + w.y*a.y + w.z*a.z + w.w*a.w;
    }
    float s = y;
    #pragma unroll
    for (int off = 1; off < 64; off <<= 1) s += __shfl_xor(s, off);
    float mean = s * (1.0f / 64.0f);
    float dv = y - mean;
    float s2 = dv * dv;
    #pragma unroll
    for (int off = 1; off < 64; off <<= 1) s2 += __shfl_xor(s2, off);
    float var = s2 * (1.0f / 64.0f);
    float hv = dv / sqrtf(var + 1e-5f) * ln1_g[e] + ln1_b[e];
    hv = fmaxf(hv, 0.f);
    float lp = hv * g2_w[e];
    #pragma unroll
    for (int off = 1; off < 64; off <<= 1) lp += __shfl_xor(lp, off);
    if (e == 0) {
      float logit = lp + g2_b[0];
      float temp = fminf(fmaxf(gate_temp[0], 0.1f), 5.0f);
      float gate = 1.0f / (1.0f + expf(-logit / temp));
      if (deg <= 0) gate = 0.f;
      gateS = gate;
    }
  }
  __syncthreads();
  float o = tanhf(sEs[tid] + gateS * aggS[tid]);
  outp[tid] = o;
  outpb[tid] = f2bf(o);
}

// ============ double-buffered LDS MFMA bf16 GEMM. lstm_mode: 0 none, 1 step, 2 first step.
// LSTM modes: j=gate permutation (gate=j, unit u=bn*32+wnx*16+col); gq in C-fragment order
// (fb=(blk*4+wave)*64+lane); cstate bf16 fragment order. If sgdot!=null on lstm_mode==1,
// the h write is replaced by a fused dot: out[m] += sum_u h[m][u]*sg[u] (atomicAdd).
template<int K>
__global__ __launch_bounds__(256) void mfma_gemm(
    const u16* __restrict__ A, int lda,
    const u16* __restrict__ W, int ldw,
    int N,
    float* __restrict__ Cout, u16* __restrict__ Cbf,
    const float* __restrict__ bias0,
    const u16* __restrict__ gqin,       // lstm_mode==1: fragment-order gates input
    u16* __restrict__ gqout,            // lstm_mode==2: fragment-order gates output
    int relu, int lstm_mode,
    u16* __restrict__ cstate, const float* __restrict__ qe,
    u16* __restrict__ hbf,
    const float* __restrict__ sgdot, float* __restrict__ dotout)
{
  __shared__ u16 As[2][128 * 32];
  __shared__ u16 Bs[2][128 * 32];
  __shared__ float dotS[4][4][16];
  int tid = threadIdx.x;
  int nb = N >> 7;
  int bn = blockIdx.x % nb, bm = blockIdx.x / nb;
  int lane = tid & 63, wave = tid >> 6;
  int wm = (wave & 1) * 64, wn = (wave >> 1) * 64;
  int col = lane & 15, quad = lane >> 4;

  // ---- epilogue input prefetch (latency hides under the K-loop) ----
  u16 gqa[64]; u16 cpv[16]; float qev[16]; float scv[4]; float sgv = 0.f;
  int u = 0; long fb = 0;
  if (lstm_mode) {
    u = bn * 32 + (wave >> 1) * 16 + col;
    fb = ((long)blockIdx.x * 4 + wave) * 64 + lane;
    #pragma unroll
    for (int j = 0; j < 4; ++j)
      scv[j] = bias0[bn * 128 + (wave >> 1) * 64 + j * 16 + col];
    if (lstm_mode == 1) {
      const short8* gp = (const short8*)(gqin + fb * 64);
      #pragma unroll
      for (int t = 0; t < 8; ++t) *(short8*)&gqa[t * 8] = gp[t];
      const short8* cp = (const short8*)(cstate + fb * 16);
      #pragma unroll
      for (int t = 0; t < 2; ++t) *(short8*)&cpv[t * 8] = cp[t];
    }
    if (u < DM) {
      if (sgdot) sgv = sgdot[u];
      #pragma unroll
      for (int i = 0; i < 4; ++i)
        #pragma unroll
        for (int r = 0; r < 4; ++r) {
          int m = bm * 128 + (wave & 1) * 64 + i * 16 + quad * 4 + r;
          qev[i * 4 + r] = qe[(long)m * DM + u];
        }
    }
  }

  floatx4 acc[4][4];
  #pragma unroll
  for (int i = 0; i < 4; ++i)
    #pragma unroll
    for (int j = 0; j < 4; ++j) { floatx4 z = {0.f,0.f,0.f,0.f}; acc[i][j] = z; }

  // issue first tile
  #pragma unroll
  for (int t = 0; t < 2; ++t) {
    int c = t * 256 + tid;
    int r = c >> 2, o = c & 3;
    int og = o ^ (r & 3);
    gl2lds16(A + (long)(bm * 128 + r) * lda + 0 + og * 8, &As[0][(size_t)c * 8]);
    gl2lds16(W + (long)(bn * 128 + r) * ldw + 0 + og * 8, &Bs[0][(size_t)c * 8]);
  }

  for (int k0 = 0; k0 < K; k0 += 32) {
    int cur = (k0 >> 5) & 1;
    __syncthreads();
    if (k0 + 32 < K) {
      int nxt = cur ^ 1;
      #pragma unroll
      for (int t = 0; t < 2; ++t) {
        int c = t * 256 + tid;
        int r = c >> 2, o = c & 3;
        int og = o ^ (r & 3);
        gl2lds16(A + (long)(bm * 128 + r) * lda + (k0 + 32) + og * 8, &As[nxt][(size_t)c * 8]);
        gl2lds16(W + (long)(bn * 128 + r) * ldw + (k0 + 32) + og * 8, &Bs[nxt][(size_t)c * 8]);
      }
    }
    short8 af[4], bfr[4];
    #pragma unroll
    for (int i = 0; i < 4; ++i) {
      int ra = wm + i * 16 + col;
      af[i] = *(const short8*)&As[cur][(size_t)(ra * 4 + (quad ^ (ra & 3))) * 8];
      int rb = wn + i * 16 + col;
      bfr[i] = *(const short8*)&Bs[cur][(size_t)(rb * 4 + (quad ^ (rb & 3))) * 8];
    }
    #pragma unroll
    for (int i = 0; i < 4; ++i)
      #pragma unroll
      for (int j = 0; j < 4; ++j)
        acc[i][j] = __builtin_amdgcn_mfma_f32_16x16x32_bf16(af[i], bfr[j], acc[i][j], 0, 0, 0);
  }

  if (lstm_mode) {
    u16 cnew[16];
    float dsum[16];
    #pragma unroll
    for (int i = 0; i < 4; ++i) {
      #pragma unroll
      for (int r = 0; r < 4; ++r) {
        float gI = acc[i][0][r] + scv[0];
        float gF = acc[i][1][r] + scv[1];
        float gG = acc[i][2][r] + scv[2];
        float gO = acc[i][3][r] + scv[3];
        if (lstm_mode == 1) {
          gI += bf2f(gqa[(i * 4 + 0) * 4 + r]);
          gF += bf2f(gqa[(i * 4 + 1) * 4 + r]);
          gG += bf2f(gqa[(i * 4 + 2) * 4 + r]);
          gO += bf2f(gqa[(i * 4 + 3) * 4 + r]);
        }
        float cp = (lstm_mode == 2) ? 0.f : bf2f(cpv[i * 4 + r]);
        float cn = sigf(gF) * cp + sigf(gI) * tanh_fast(gG);
        cnew[i * 4 + r] = f2bf(cn);
        float hv = 0.f;
        if (u < DM) hv = qev[i * 4 + r] + sigf(gO) * tanh_fast(cn);
        if (sgdot) dsum[i * 4 + r] = hv * sgv;
        else if (u < DM) {
          int m = bm * 128 + (wave & 1) * 64 + i * 16 + quad * 4 + r;
          hbf[(long)m * DM + u] = f2bf(hv);
        }
      }
    }
    if (!sgdot || bn * 32 < DM) {   // last-step blocks with bn>=8 contribute nothing
      short8* cp = (short8*)(cstate + fb * 16);
      #pragma unroll
      for (int t = 0; t < 2; ++t) cp[t] = *(short8*)&cnew[t * 8];
    }
    if (lstm_mode == 2) {
      u16 ga[64];
      #pragma unroll
      for (int i = 0; i < 4; ++i)
        #pragma unroll
        for (int j = 0; j < 4; ++j)
          #pragma unroll
          for (int r = 0; r < 4; ++r)
            ga[(i * 4 + j) * 4 + r] = f2bf(acc[i][j][r] + scv[j]);
      short8* gp = (short8*)(gqout + fb * 64);
      #pragma unroll
      for (int t = 0; t < 8; ++t) gp[t] = *(short8*)&ga[t * 8];
    }
    if (sgdot && bn < (DM / 32)) {
      // reduce dsum over the 16 col-lanes (u varies with col; m does not)
      #pragma unroll
      for (int t = 0; t < 16; ++t) {
        float v = dsum[t];
        v += __shfl_xor(v, 1);
        v += __shfl_xor(v, 2);
        v += __shfl_xor(v, 4);
        v += __shfl_xor(v, 8);
        dsum[t] = v;
      }
      if (col == 0) {
        #pragma unroll
        for (int t = 0; t < 16; ++t) dotS[wave][quad][t] = dsum[t];
      }
      __syncthreads();
      if (tid < 128) {
        int m = tid;
        int h = (m >= 64) ? 1 : 0;
        int q = (m >> 2) & 3;
        int idx = ((m & 63) >> 4) * 4 + (m & 3);
        float v = dotS[h][q][idx] + dotS[h + 2][q][idx];
        atomicAdd(dotout + bm * 128 + m, v);
      }
    }
  } else {
    int gm0 = bm * 128 + wm + quad * 4;
    int gn0 = bn * 128 + wn + col;
    #pragma unroll
    for (int i = 0; i < 4; ++i) {
      #pragma unroll
      for (int j = 0; j < 4; ++j) {
        int n = gn0 + j * 16;
        #pragma unroll
        for (int r = 0; r < 4; ++r) {
          int m = gm0 + i * 16 + r;
          float v = acc[i][j][r];
          if (bias0) v += bias0[n];
          if (relu) v = fmaxf(v, 0.f);
          if (Cout) Cout[(long)m * N + n] = v;
          if (Cbf)  Cbf[(long)m * N + n] = f2bf(v);
        }
      }
    }
  }
}

// ============ weight casts + j=gate permuted layouts ============
// position p in [0,2048): g=(p>>4)&3, u=(p>>7)*32+((p>>6)&1)*16+(p&15), orig row n=g*512+u
__global__ void prep_cast(
    const float* __restrict__ p1, const float* __restrict__ p2,
    const float* __restrict__ gcnw, const float* __restrict__ wih,
    const float* __restrict__ whh, const float* __restrict__ bih,
    const float* __restrict__ bhh,
    u16* __restrict__ p1b, u16* __restrict__ p2b, u16* __restrict__ gcnb,
    u16* __restrict__ wihb, u16* __restrict__ whhb, float* __restrict__ bihh)
{
  int gid = blockIdx.x * 256 + threadIdx.x;
  if (gid < 131072) { p1b[gid] = f2bf(p1[gid]); }
  else if (gid < 262144) { int i = gid - 131072; p2b[i] = f2bf(p2[i]); }
  else if (gid < 294912) { int i = gid - 262144; gcnb[i] = f2bf(gcnw[i]); }
  else if (gid < 819200) {
    int i = gid - 294912; int p = i >> 8, k = i & 255;
    int g = (p >> 4) & 3, uu = (p >> 7) * 32 + ((p >> 6) & 1) * 16 + (p & 15);
    int n = g * 512 + uu;
    wihb[i] = f2bf(wih[(long)n * DM + k]);
  } else if (gid < 1343488) {
    int i = gid - 819200; int p = i >> 8, k = i & 255;
    int g = (p >> 4) & 3, uu = (p >> 7) * 32 + ((p >> 6) & 1) * 16 + (p & 15);
    int n = g * 512 + uu;
    whhb[i] = f2bf(whh[(long)n * LH + k]);
  } else if (gid < 1345536) {
    int p = gid - 1343488;
    int g = (p >> 4) & 3, uu = (p >> 7) * 32 + ((p >> 6) & 1) * 16 + (p & 15);
    int n = g * 512 + uu;
    bihh[p] = bih[n] + bhh[n];
  }
}

// ============ residual layernorm -> qe (fp32 + bf16), rows 0..4100 ============
__global__ __launch_bounds__(256) void ln_residual_kernel(
    const float* __restrict__ h2buf, const float* __restrict__ xbuf,
    const float* __restrict__ lng, const float* __restrict__ lnb,
    float* __restrict__ out, u16* __restrict__ outb)
{
  __shared__ float red[4];
  int r = blockIdx.x, tid = threadIdx.x;
  float v = h2buf[(long)r * DM + tid] + xbuf[(long)r * DM + tid];
  float s = v;
  #pragma unroll
  for (int off = 1; off < 64; off <<= 1) s += __shfl_xor(s, off);
  if ((tid & 63) == 0) red[tid >> 6] = s;
  __syncthreads();
  float mean = (red[0] + red[1] + red[2] + red[3]) * (1.0f / 256.0f);
  __syncthreads();
  float dv = v - mean;
  float s2 = dv * dv;
  #pragma unroll
  for (int off = 1; off < 64; off <<= 1) s2 += __shfl_xor(s2, off);
  if ((tid & 63) == 0) red[tid >> 6] = s2;
  __syncthreads();
  float var = (red[0] + red[1] + red[2] + red[3]) * (1.0f / 256.0f);
  float o = dv / sqrtf(var + 1e-5f) * lng[tid] + lnb[tid];
  out[(long)r * DM + tid] = o;
  outb[(long)r * DM + tid] = f2bf(o);
}

// ============ sg (mean of qe rows 4096..4100) + permuted s_corr ============
__global__ __launch_bounds__(256) void scorr_kernel(
    const float* __restrict__ qe, const float* __restrict__ whh,
    float* __restrict__ sg, float* __restrict__ s_corr_perm)
{
  __shared__ float sgS[DM];
  int tid = threadIdx.x;
  {
    float v = 0.f;
    #pragma unroll
    for (int r = 0; r < F_SUP; ++r) v += qe[(long)(BQ + r) * DM + tid];
    v *= (1.0f / (float)F_SUP);
    sgS[tid] = v;
    if (blockIdx.x == 0) sg[tid] = v;
  }
  __syncthreads();
  int wave = tid >> 6, lane = tid & 63;
  int n = blockIdx.x * 4 + wave;   // orig row 0..2047
  float4 w = *(const float4*)(whh + (long)n * LH + DM + lane * 4);
  float4 s = *(const float4*)&sgS[lane * 4];
  float d = w.x*s.x + w.y*s.y + w.z*s.z + w.w*s.w;
  #pragma unroll
  for (int off = 1; off < 64; off <<= 1) d += __shfl_xor(d, off);
  if (lane == 0) {
    int g = n >> 9, uu = n & 511;
    int p = (uu >> 5) * 128 + ((uu >> 4) & 1) * 64 + g * 16 + (uu & 15);
    s_corr_perm[p] = d;
  }
}

extern "C" void kernel_launch(void* const* d_in, const int* in_sizes, int n_in,
                              void* d_out, int out_size, void* d_ws, size_t ws_size,
                              hipStream_t stream)
{
  const int*   query    = (const int*)  d_in[0];
  const int*   support  = (const int*)  d_in[1];
  const int*   q_l1     = (const int*)  d_in[2];
  const int*   q_deg_l  = (const int*)  d_in[3];
  const int*   q_r1     = (const int*)  d_in[4];
  const int*   q_deg_r  = (const int*)  d_in[5];
  const int*   s_l1     = (const int*)  d_in[6];
  const int*   s_deg_l  = (const int*)  d_in[7];
  const int*   s_r1     = (const int*)  d_in[8];
  const int*   s_deg_r  = (const int*)  d_in[9];
  const float* symbol_emb = (const float*)d_in[10];
  const float* gcn_w_w  = (const float*)d_in[11];
  const float* gcn_w_b  = (const float*)d_in[12];
  const float* gcn_b    = (const float*)d_in[13];
  const float* g1_w     = (const float*)d_in[14];
  const float* g1_b     = (const float*)d_in[15];
  const float* ln1_g    = (const float*)d_in[16];
  const float* ln1_b    = (const float*)d_in[17];
  const float* g2_w     = (const float*)d_in[18];
  const float* g2_b     = (const float*)d_in[19];
  const float* gate_temp= (const float*)d_in[20];
  const float* se_p1_w  = (const float*)d_in[21];
  const float* se_p1_b  = (const float*)d_in[22];
  const float* se_p2_w  = (const float*)d_in[23];
  const float* se_p2_b  = (const float*)d_in[24];
  const float* se_ln_g  = (const float*)d_in[25];
  const float* se_ln_b  = (const float*)d_in[26];
  const float* w_ih     = (const float*)d_in[27];
  const float* w_hh     = (const float*)d_in[28];
  const float* b_ih     = (const float*)d_in[29];
  const float* b_hh     = (const float*)d_in[30];

  float* ws = (float*)d_ws;
  size_t off = 0;
  float* projF   = ws + off; off += (size_t)MROWS * 128 / 2;      // bf16 proj
  float* idxF    = ws + off; off += (size_t)MROWS * 2;
  float* qv      = ws + off; off += (size_t)MQ * DM;
  float* qe      = ws + off; off += (size_t)MQ * DM;
  float* qv_bfF  = ws + off; off += (size_t)MQ * DM / 2;
  float* qe_bfF  = ws + off; off += (size_t)MQ * DM / 2;
  float* h1bF    = ws + off; off += (size_t)MQ * DI / 2;
  float* H2      = ws + off; off += (size_t)MQ * DM;
  float* gqbF    = ws + off; off += (size_t)BQ * NG / 2;          // fragment-order gates (bf16)
  float* cstateF = ws + off; off += (size_t)BQ * LH / 2;          // fragment-order c (bf16)
  float* hbf0F   = ws + off; off += (size_t)BQ * DM / 2;
  float* hbf1F   = ws + off; off += (size_t)BQ * DM / 2;
  float* p1bF    = ws + off; off += 131072 / 2;
  float* p2bF    = ws + off; off += 131072 / 2;
  float* gcnbF   = ws + off; off += 32768 / 2;
  float* wihbF   = ws + off; off += 524288 / 2;
  float* whhbF   = ws + off; off += 524288 / 2;
  float* bihh    = ws + off; off += 2048;
  float* sg      = ws + off; off += 256;
  float* s_corr  = ws + off; off += 2048;
  float* metaF   = ws + off; off += 8448;

  u16* proj   = (u16*)projF;
  int* idxA   = (int*)idxF;
  u16* qv_bf  = (u16*)qv_bfF;
  u16* qe_bf  = (u16*)qe_bfF;
  u16* H1_bf  = (u16*)h1bF;
  u16* gq_fr  = (u16*)gqbF;
  u16* cstate = (u16*)cstateF;
  u16* hbf0   = (u16*)hbf0F;
  u16* hbf1   = (u16*)hbf1F;
  u16* p1b    = (u16*)p1bF;
  u16* p2b    = (u16*)p2bF;
  u16* gcnb   = (u16*)gcnbF;
  u16* wihb   = (u16*)wihbF;
  u16* whhb   = (u16*)whhbF;
  int* meta   = (int*)metaF;
  float* outF = (float*)d_out;

  // zero output (last LSTM step accumulates the final dot via atomics)
  hipMemsetAsync(d_out, 0, (size_t)out_size * sizeof(float), stream);

  // 0. weight casts / permutes
  prep_cast<<<5256, 256, 0, stream>>>(se_p1_w, se_p2_w, gcn_w_w, w_ih, w_hh, b_ih, b_hh,
                                      p1b, p2b, gcnb, wihb, whhb, bihh);

  // 1. gather + top-k -> selected ids
  nbr_topk_kernel<<<2 * BQ + 2 * F_SUP, 256, 0, stream>>>(
      query, support, q_l1, q_r1, s_l1, s_r1, symbol_emb, idxA, meta);

  // 2. proj = emb[idx] @ gcn_w^T   (M=82048, N=128, K=256), LDS-staged gather GEMM
  proj_gather_gemm<<<MROWS / 128, 256, 0, stream>>>(idxA, symbol_emb, gcnb, proj);

  // 3. leaky/sum + gate MLP + tanh -> qv rows 0..4100 (query + support)
  nbr_post_kernel<<<2 * BQ + 2 * F_SUP, 128, 0, stream>>>(
      query, support, q_deg_l, q_deg_r, s_deg_l, s_deg_r, symbol_emb,
      proj, meta, gcn_w_b, gcn_b, g1_w, g1_b, ln1_g, ln1_b, g2_w, g2_b, gate_temp,
      qv, qv_bf);

  // 4. encoder (query + 5 support rows ride along)
  mfma_gemm<256><<<(MQ / 128) * (DI / 128), 256, 0, stream>>>(qv_bf, 256, p1b, 256, DI,
      nullptr, H1_bf, se_p1_b, nullptr, nullptr, 1, 0, nullptr, nullptr, nullptr, nullptr, nullptr);
  mfma_gemm<512><<<(MQ / 128) * (DM / 128), 256, 0, stream>>>(H1_bf, 512, p2b, 512, DM,
      H2, nullptr, se_p2_b, nullptr, nullptr, 0, 0, nullptr, nullptr, nullptr, nullptr, nullptr);
  ln_residual_kernel<<<BQ + F_SUP, 256, 0, stream>>>(H2, qv, se_ln_g, se_ln_b, qe, qe_bf);

  // 5. support_g + permuted s_corr
  scorr_kernel<<<512, 256, 0, stream>>>(qe, w_hh, sg, s_corr);

  // 6. gq = qe@w_ih_perm^T + (b_ih+b_hh); fused LSTM step 1; gates stored fragment-order
  mfma_gemm<256><<<(BQ / 128) * (NG / 128), 256, 0, stream>>>(qe_bf, 256, wihb, 256, NG,
      nullptr, nullptr, bihh, nullptr, gq_fr, 0, 2, cstate, qe, hbf0, nullptr, nullptr);

  // 7. steps 2..3: fused GEMM + in-thread LSTM epilogue (h ping-pong)
  mfma_gemm<256><<<(BQ / 128) * (NG / 128), 256, 0, stream>>>(hbf0, 256, whhb, 256, NG,
      nullptr, nullptr, s_corr, gq_fr, nullptr, 0, 1, cstate, qe, hbf1, nullptr, nullptr);
  mfma_gemm<256><<<(BQ / 128) * (NG / 128), 256, 0, stream>>>(hbf1, 256, whhb, 256, NG,
      nullptr, nullptr, s_corr, gq_fr, nullptr, 0, 1, cstate, qe, hbf0, nullptr, nullptr);

  // 8. step 4 with fused final dot: out[m] = dot(h[m], sg) accumulated via atomics
  mfma_gemm<256><<<(BQ / 128) * (NG / 128), 256, 0, stream>>>(hbf0, 256, whhb, 256, NG,
      nullptr, nullptr, s_corr, gq_fr, nullptr, 0, 1, cstate, qe, nullptr, sg, outF);
}